// Round 1
// baseline (929.587 us; speedup 1.0000x reference)
//
#include <hip/hip_runtime.h>
#include <hip/hip_bf16.h>
#include <cstdint>

typedef unsigned short u16;
typedef __attribute__((ext_vector_type(8))) _Float16 f16x8;
typedef __attribute__((ext_vector_type(4))) float f32x4;
typedef __attribute__((ext_vector_type(8))) unsigned short u16x8;

typedef const __attribute__((address_space(1))) void* gas1p;
typedef __attribute__((address_space(3))) void* las3p;

__device__ __forceinline__ void gld_lds16(const void* g, void* l) {
    __builtin_amdgcn_global_load_lds((gas1p)g, (las3p)l, 16, 0, 0);
}

__device__ __forceinline__ u16 f2h(float f) {
    _Float16 h = (_Float16)f;
    return __builtin_bit_cast(u16, h);
}

// ---------------- prep: x fp32 -> fp16 ----------------
__global__ void cvt_x_kernel(const float4* __restrict__ x, u16* __restrict__ xb) {
    size_t i = (size_t)blockIdx.x * blockDim.x + threadIdx.x;
    float4 a = x[2 * i];
    float4 b = x[2 * i + 1];
    u16x8 o;
    o[0] = f2h(a.x); o[1] = f2h(a.y); o[2] = f2h(a.z); o[3] = f2h(a.w);
    o[4] = f2h(b.x); o[5] = f2h(b.y); o[6] = f2h(b.z); o[7] = f2h(b.w);
    *(u16x8*)&xb[i * 8] = o;
}

// ---------------- prep: weight norm ----------------
// partial[seg][n] = sum over rows in seg of v[k][n]^2   (grid: (N/64, 8), block 256)
__global__ void wn_partial(const float* __restrict__ v, float* __restrict__ partial,
                           int K, int N) {
    int lane = threadIdx.x & 63;
    int tr = threadIdx.x >> 6;
    int n = blockIdx.x * 64 + lane;
    int kseg = K >> 3;
    int kbeg = blockIdx.y * kseg;
    float s = 0.f;
    for (int k = kbeg + tr; k < kbeg + kseg; k += 4) {
        float x = v[(size_t)k * N + n];
        s += x * x;
    }
    __shared__ float red[4][64];
    red[tr][lane] = s;
    __syncthreads();
    if (tr == 0)
        partial[blockIdx.y * N + n] = red[0][lane] + red[1][lane] + red[2][lane] + red[3][lane];
}

__global__ void wn_scale(const float* __restrict__ partial, const float* __restrict__ g,
                         float* __restrict__ scale, int N) {
    int n = blockIdx.x * 256 + threadIdx.x;
    if (n < N) {
        float s = 0.f;
        for (int i = 0; i < 8; i++) s += partial[i * N + n];
        scale[n] = g[n] / sqrtf(s);
    }
}

// wT[n][k] = fp16( v[k][n] * scale[n] )   (grid: (N/64, 8), block 256)
__global__ void wn_write(const float* __restrict__ v, const float* __restrict__ scale,
                         u16* __restrict__ wT, int K, int N) {
    int lane = threadIdx.x & 63;
    int tr = threadIdx.x >> 6;
    int n = blockIdx.x * 64 + lane;
    int kseg = K >> 3;
    int kbeg = blockIdx.y * kseg;
    float sc = scale[n];
    for (int k = kbeg + tr; k < kbeg + kseg; k += 4)
        wT[(size_t)n * K + k] = f2h(v[(size_t)k * N + n] * sc);
}

// ---------------- main GEMM: C = act(A @ B), A:[M,K] fp16, Bt:[N,K] fp16 ----------------
// m97 structure: 128x128 tile, BK=64, 4 waves (2x2) of 64x64, mfma_f32_16x16x32_f16,
// global_load_lds width 16, 2-barrier K-loop, XCD-bijective swizzle.
template<int N, int K, bool ACT, bool OUTF32>
__global__ __launch_bounds__(256) void gemm_mlp(
    const u16* __restrict__ A, const u16* __restrict__ Bt,
    u16* __restrict__ Ch, float* __restrict__ Cf)
{
    constexpr int M = 65536;
    constexpr int NT = N / 128;
    constexpr int NWG = (M / 128) * NT;

    __shared__ alignas(16) u16 ldsA[128 * 64];
    __shared__ alignas(16) u16 ldsB[128 * 64];

    int bid = blockIdx.x;
    // bijective XCD swizzle (NWG % 8 == 0 for all instantiations)
    int wk = (bid & 7) * (NWG >> 3) + (bid >> 3);
    int tm = wk / NT;
    int tn = wk % NT;
    long m0 = (long)tm * 128;
    int n0 = tn * 128;

    int tid = threadIdx.x;
    int lane = tid & 63;
    int wm = ((tid >> 7) & 1) * 64;   // wave row offset
    int wn = ((tid >> 6) & 1) * 64;   // wave col offset

    // staging addresses: thread covers row (tid>>3)+32*c, cols (tid&7)*8..+8 of the tile
    const u16* Ab = A + m0 * K + (size_t)(tid >> 3) * K + (tid & 7) * 8;
    const u16* Bb = Bt + (long)n0 * K + (size_t)(tid >> 3) * K + (tid & 7) * 8;
    u16* ldsAw = &ldsA[tid * 8];
    u16* ldsBw = &ldsB[tid * 8];

    f32x4 acc[4][4] = {};

    for (int k0 = 0; k0 < K; k0 += 64) {
#pragma unroll
        for (int c = 0; c < 4; c++) {
            gld_lds16(Ab + k0 + c * (32 * K), ldsAw + c * 2048);
            gld_lds16(Bb + k0 + c * (32 * K), ldsBw + c * 2048);
        }
        asm volatile("s_waitcnt vmcnt(0)" ::: "memory");
        __syncthreads();
#pragma unroll
        for (int kk = 0; kk < 2; kk++) {
            f16x8 a[4], b[4];
            int kof = kk * 32 + (lane >> 4) * 8;
#pragma unroll
            for (int i = 0; i < 4; i++)
                a[i] = *(const f16x8*)&ldsA[(wm + i * 16 + (lane & 15)) * 64 + kof];
#pragma unroll
            for (int j = 0; j < 4; j++)
                b[j] = *(const f16x8*)&ldsB[(wn + j * 16 + (lane & 15)) * 64 + kof];
#pragma unroll
            for (int i = 0; i < 4; i++)
#pragma unroll
                for (int j = 0; j < 4; j++)
                    acc[i][j] = __builtin_amdgcn_mfma_f32_16x16x32_f16(a[i], b[j], acc[i][j], 0, 0, 0);
        }
        __syncthreads();
    }

    // epilogue: C layout col = lane&15, row = (lane>>4)*4 + reg  [m89 verified]
    long crow0 = m0 + wm + ((lane >> 4) << 2);
    int ccol0 = n0 + wn + (lane & 15);
#pragma unroll
    for (int i = 0; i < 4; i++) {
#pragma unroll
        for (int r = 0; r < 4; r++) {
            long row = crow0 + i * 16 + r;
#pragma unroll
            for (int j = 0; j < 4; j++) {
                float v = acc[i][j][r];
                if (ACT) v = fmaxf(v, 0.f) + __logf(1.f + __expf(-fabsf(v)));
                long idx = row * N + ccol0 + j * 16;
                if (OUTF32) Cf[idx] = v;
                else        Ch[idx] = f2h(v);
            }
        }
    }
}

// ---------------- launch ----------------
extern "C" void kernel_launch(void* const* d_in, const int* in_sizes, int n_in,
                              void* d_out, int out_size, void* d_ws, size_t ws_size,
                              hipStream_t stream) {
    const float* x  = (const float*)d_in[0];
    const float* v1 = (const float*)d_in[1];
    const float* g1 = (const float*)d_in[2];
    const float* v2 = (const float*)d_in[3];
    const float* g2 = (const float*)d_in[4];
    const float* v3 = (const float*)d_in[5];
    const float* g3 = (const float*)d_in[6];
    const float* v4 = (const float*)d_in[7];
    const float* g4 = (const float*)d_in[8];
    const float* v5 = (const float*)d_in[9];
    const float* g5 = (const float*)d_in[10];
    float* out = (float*)d_out;

    const int M = 65536;
    char* ws = (char*)d_ws;
    u16* bufA = (u16*)(ws);                          // 128 MB: h (M x 1024 fp16)
    u16* bufB = (u16*)(ws + 0x8000000ULL);           // 128 MB: h / xb
    u16* w1T  = (u16*)(ws + 0x10000000ULL);          // [1024][512]
    u16* w2T  = w1T + 1024 * 512;                    // [1024][1024]
    u16* w3T  = w2T + 1024 * 1024;
    u16* w4T  = w3T + 1024 * 1024;
    u16* w5T  = w4T + 1024 * 1024;                   // [512][1024]
    float* partial = (float*)(ws + 0x10800000ULL);   // 8 x 1024
    float* scale   = partial + 8 * 1024;             // 1024

    // x -> fp16 into bufB (M*512 elems, 8 per thread)
    cvt_x_kernel<<<(M * 512) / (256 * 8), 256, 0, stream>>>((const float4*)x, bufB);

    // weight-norm prep (deterministic two-pass)
    auto prep = [&](const float* v, const float* g, u16* wT, int K, int N) {
        wn_partial<<<dim3(N / 64, 8), 256, 0, stream>>>(v, partial, K, N);
        wn_scale<<<(N + 255) / 256, 256, 0, stream>>>(partial, g, scale, N);
        wn_write<<<dim3(N / 64, 8), 256, 0, stream>>>(v, scale, wT, K, N);
    };
    prep(v1, g1, w1T, 512, 1024);
    prep(v2, g2, w2T, 1024, 1024);
    prep(v3, g3, w3T, 1024, 1024);
    prep(v4, g4, w4T, 1024, 1024);
    prep(v5, g5, w5T, 1024, 512);

    // 5-layer MLP chain
    gemm_mlp<1024, 512, true, false><<<4096, 256, 0, stream>>>(bufB, w1T, bufA, nullptr);
    gemm_mlp<1024, 1024, true, false><<<4096, 256, 0, stream>>>(bufA, w2T, bufB, nullptr);
    gemm_mlp<1024, 1024, true, false><<<4096, 256, 0, stream>>>(bufB, w3T, bufA, nullptr);
    gemm_mlp<1024, 1024, true, false><<<4096, 256, 0, stream>>>(bufA, w4T, bufB, nullptr);
    gemm_mlp<512, 1024, false, true><<<2048, 256, 0, stream>>>(bufB, w5T, nullptr, out);

    (void)in_sizes; (void)n_in; (void)out_size; (void)ws_size;
}

// Round 2
// 825.078 us; speedup vs baseline: 1.1267x; 1.1267x over previous
//
#include <hip/hip_runtime.h>
#include <hip/hip_bf16.h>
#include <cstdint>

typedef unsigned short u16;
typedef __attribute__((ext_vector_type(8))) _Float16 f16x8;
typedef __attribute__((ext_vector_type(4))) float f32x4;
typedef __attribute__((ext_vector_type(8))) unsigned short u16x8;

typedef const __attribute__((address_space(1))) void* gas1p;
typedef __attribute__((address_space(3))) void* las3p;

__device__ __forceinline__ void gld_lds16(const void* g, void* l) {
    __builtin_amdgcn_global_load_lds((gas1p)g, (las3p)l, 16, 0, 0);
}

__device__ __forceinline__ u16 f2h(float f) {
    _Float16 h = (_Float16)f;
    return __builtin_bit_cast(u16, h);
}

// ---------------- prep: x fp32 -> fp16 ----------------
__global__ void cvt_x_kernel(const float4* __restrict__ x, u16* __restrict__ xb) {
    size_t i = (size_t)blockIdx.x * blockDim.x + threadIdx.x;
    float4 a = x[2 * i];
    float4 b = x[2 * i + 1];
    u16x8 o;
    o[0] = f2h(a.x); o[1] = f2h(a.y); o[2] = f2h(a.z); o[3] = f2h(a.w);
    o[4] = f2h(b.x); o[5] = f2h(b.y); o[6] = f2h(b.z); o[7] = f2h(b.w);
    *(u16x8*)&xb[i * 8] = o;
}

// ---------------- prep: weight norm (deterministic two-pass) ----------------
__global__ void wn_partial(const float* __restrict__ v, float* __restrict__ partial,
                           int K, int N) {
    int lane = threadIdx.x & 63;
    int tr = threadIdx.x >> 6;
    int n = blockIdx.x * 64 + lane;
    int kseg = K >> 3;
    int kbeg = blockIdx.y * kseg;
    float s = 0.f;
    for (int k = kbeg + tr; k < kbeg + kseg; k += 4) {
        float x = v[(size_t)k * N + n];
        s += x * x;
    }
    __shared__ float red[4][64];
    red[tr][lane] = s;
    __syncthreads();
    if (tr == 0)
        partial[blockIdx.y * N + n] = red[0][lane] + red[1][lane] + red[2][lane] + red[3][lane];
}

__global__ void wn_scale(const float* __restrict__ partial, const float* __restrict__ g,
                         float* __restrict__ scale, int N) {
    int n = blockIdx.x * 256 + threadIdx.x;
    if (n < N) {
        float s = 0.f;
        for (int i = 0; i < 8; i++) s += partial[i * N + n];
        scale[n] = g[n] / sqrtf(s);
    }
}

__global__ void wn_write(const float* __restrict__ v, const float* __restrict__ scale,
                         u16* __restrict__ wT, int K, int N) {
    int lane = threadIdx.x & 63;
    int tr = threadIdx.x >> 6;
    int n = blockIdx.x * 64 + lane;
    int kseg = K >> 3;
    int kbeg = blockIdx.y * kseg;
    float sc = scale[n];
    for (int k = kbeg + tr; k < kbeg + kseg; k += 4)
        wT[(size_t)n * K + k] = f2h(v[(size_t)k * N + n] * sc);
}

// ---------------- main GEMM: 256x256 tile, BK=64, 8 waves, 4-phase schedule ----
// A:[M,K] fp16 row-major, Bt:[N,K] fp16 (B transposed). C = act(A@B).
// LDS: 2 buffers. A buf: [256 rows][64 k], swizzled slot^=(row&7).
//      B buf: stripe-major 2 sets x [128 local rows][64 k] (set = qn stripe).
// Staging per tile t (2 gld_lds per phase): P1: A(t+1).Q1,Q3  P2: B(t+1).set0
//   P3: A(t+2).Q0,Q2  P4: B(t+1).set1.  Drains: vmcnt(2)@P1, vmcnt(4)@P4.
template<int N, int K, bool ACT, bool OUTF32>
__global__ __launch_bounds__(512, 2) void gemm_mlp(
    const u16* __restrict__ A, const u16* __restrict__ Bt,
    u16* __restrict__ Ch, float* __restrict__ Cf)
{
    constexpr int M = 65536;
    constexpr int NT = K / 64;
    constexpr int NTN = N / 256;
    constexpr int NWG = (M / 256) * NTN;

    __shared__ u16 sA[2][256 * 64];
    __shared__ u16 sB[2][2 * 128 * 64];

    const int bid = blockIdx.x;
    const int wk = (bid & 7) * (NWG >> 3) + (bid >> 3);   // bijective: NWG%8==0
    const int tm = wk / NTN, tn = wk % NTN;
    const long m0 = (long)tm * 256;
    const int n0 = tn * 256;

    const int tid = threadIdx.x;
    const int lane = tid & 63;
    const int wid = tid >> 6;
    const int wm = (wid >> 2) * 128;   // 2 M-waves
    const int wn = (wid & 3) * 64;     // 4 N-waves

    // ---- staging addresses (inverse-swizzled global source, linear LDS dest) ----
    const int r8 = tid >> 3;                       // staged row within 64-row chunk
    const int gcol = ((tid & 7) ^ (r8 & 7)) * 8;   // pre-swizzled k-slot
    const u16* Abase = A + (m0 + r8) * (size_t)K + gcol;
    const u16* Bbase = Bt + (size_t)(n0 + ((r8 >> 5) * 64 + (r8 & 31))) * K + gcol;
    const int dst8 = tid * 8;

    auto stageA = [&](int buf, int t, int q) {
        gld_lds16(Abase + (size_t)q * (64 * (size_t)K) + (size_t)t * 64,
                  &sA[buf][q * 4096 + dst8]);
    };
    auto stageB = [&](int buf, int t, int s, int c) {
        gld_lds16(Bbase + (size_t)(s * 32 + c * 128) * K + (size_t)t * 64,
                  &sB[buf][s * 8192 + c * 4096 + dst8]);
    };

    // ---- fragment read bases (swizzled) ----
    const int rbase = lane & 15;
    const int co0 = ((lane >> 4) ^ (lane & 7)) * 8;           // kk=0 slot; kk=1 = ^32
    const int arow0 = (wm + rbase) * 64 + co0;
    const int brow0 = ((wn >> 6) * 32 + rbase) * 64 + co0;

    f32x4 acc[8][4] = {};
    f16x8 a[4][2], bq[2][2][2];

    auto ldA = [&](int buf, int qm) {
#pragma unroll
        for (int i = 0; i < 4; i++) {
            int base = arow0 + (qm * 64 + i * 16) * 64;
            a[i][0] = *(const f16x8*)&sA[buf][base];
            a[i][1] = *(const f16x8*)&sA[buf][base ^ 32];
        }
    };
    auto ldB = [&](int buf, int qn) {
#pragma unroll
        for (int j2 = 0; j2 < 2; j2++) {
            int base = brow0 + qn * 8192 + j2 * 1024;
            bq[qn][j2][0] = *(const f16x8*)&sB[buf][base];
            bq[qn][j2][1] = *(const f16x8*)&sB[buf][base ^ 32];
        }
    };
    auto mmaq = [&](int qm, int qn) {
        __builtin_amdgcn_s_setprio(1);
#pragma unroll
        for (int i = 0; i < 4; i++)
#pragma unroll
            for (int j2 = 0; j2 < 2; j2++) {
                f32x4 c = acc[qm * 4 + i][qn * 2 + j2];
                c = __builtin_amdgcn_mfma_f32_16x16x32_f16(a[i][0], bq[qn][j2][0], c, 0, 0, 0);
                c = __builtin_amdgcn_mfma_f32_16x16x32_f16(a[i][1], bq[qn][j2][1], c, 0, 0, 0);
                acc[qm * 4 + i][qn * 2 + j2] = c;
            }
        __builtin_amdgcn_s_setprio(0);
    };
    auto bar = [&]() {
        __builtin_amdgcn_sched_barrier(0);
        asm volatile("" ::: "memory");
        __builtin_amdgcn_s_barrier();
        asm volatile("" ::: "memory");
        __builtin_amdgcn_sched_barrier(0);
    };

    // ---- prologue: stage tiles 0 (full), A(1).Q0/Q2, in steady-state order ----
    stageA(0, 0, 0); stageA(0, 0, 2);
    stageA(0, 0, 1); stageA(0, 0, 3);
    stageB(0, 0, 0, 0); stageB(0, 0, 0, 1);
    stageA(1, 1, 0); stageA(1, 1, 2);
    stageB(0, 0, 1, 0); stageB(0, 0, 1, 1);
    asm volatile("s_waitcnt vmcnt(4)" ::: "memory");
    bar();

    // ---- main loop ----
#pragma unroll 2
    for (int t = 0; t < NT - 2; t++) {
        const int cur = t & 1, nxt = cur ^ 1;
        // P1 (qm0,qn0)
        stageA(nxt, t + 1, 1); stageA(nxt, t + 1, 3);
        ldA(cur, 0); ldB(cur, 0);
        asm volatile("s_waitcnt vmcnt(2)" ::: "memory");
        bar();
        mmaq(0, 0);
        // P2 (qm0,qn1)
        stageB(nxt, t + 1, 0, 0); stageB(nxt, t + 1, 0, 1);
        ldB(cur, 1);
        bar();
        mmaq(0, 1);
        // P3 (qm1,qn0)
        stageA(cur, t + 2, 0); stageA(cur, t + 2, 2);
        ldA(cur, 1);
        bar();
        mmaq(1, 0);
        // P4 (qm1,qn1)
        stageB(nxt, t + 1, 1, 0); stageB(nxt, t + 1, 1, 1);
        asm volatile("s_waitcnt vmcnt(4)" ::: "memory");
        bar();
        mmaq(1, 1);
    }
    // ---- t = NT-2 (no P3 stage) ----
    {
        const int t = NT - 2, cur = t & 1, nxt = cur ^ 1;
        stageA(nxt, t + 1, 1); stageA(nxt, t + 1, 3);
        ldA(cur, 0); ldB(cur, 0);
        asm volatile("s_waitcnt vmcnt(2)" ::: "memory");
        bar();
        mmaq(0, 0);
        stageB(nxt, t + 1, 0, 0); stageB(nxt, t + 1, 0, 1);
        ldB(cur, 1);
        bar();
        mmaq(0, 1);
        ldA(cur, 1);
        bar();
        mmaq(1, 0);
        stageB(nxt, t + 1, 1, 0); stageB(nxt, t + 1, 1, 1);
        asm volatile("s_waitcnt vmcnt(2)" ::: "memory");
        bar();
        mmaq(1, 1);
    }
    // ---- t = NT-1 (no staging) ----
    {
        const int cur = (NT - 1) & 1;
        ldA(cur, 0); ldB(cur, 0);
        asm volatile("s_waitcnt vmcnt(0)" ::: "memory");
        bar();
        mmaq(0, 0);
        ldB(cur, 1);
        bar();
        mmaq(0, 1);
        ldA(cur, 1);
        bar();
        mmaq(1, 0);
        bar();
        mmaq(1, 1);
    }

    // ---- epilogue: C layout col = lane&15, row = (lane>>4)*4 + reg ----
    const long crow0 = m0 + wm + ((lane >> 4) << 2);
    const int ccol0 = n0 + wn + (lane & 15);
#pragma unroll
    for (int fi = 0; fi < 8; fi++) {
#pragma unroll
        for (int r = 0; r < 4; r++) {
            const size_t rowoff = (size_t)(crow0 + fi * 16 + r) * N;
#pragma unroll
            for (int fj = 0; fj < 4; fj++) {
                float v = acc[fi][fj][r];
                if (ACT) v = fmaxf(v, 0.f) + __logf(1.f + __expf(-fabsf(v)));
                if (OUTF32) Cf[rowoff + ccol0 + fj * 16] = v;
                else        Ch[rowoff + ccol0 + fj * 16] = f2h(v);
            }
        }
    }
}

// ---------------- launch ----------------
extern "C" void kernel_launch(void* const* d_in, const int* in_sizes, int n_in,
                              void* d_out, int out_size, void* d_ws, size_t ws_size,
                              hipStream_t stream) {
    const float* x  = (const float*)d_in[0];
    const float* v1 = (const float*)d_in[1];
    const float* g1 = (const float*)d_in[2];
    const float* v2 = (const float*)d_in[3];
    const float* g2 = (const float*)d_in[4];
    const float* v3 = (const float*)d_in[5];
    const float* g3 = (const float*)d_in[6];
    const float* v4 = (const float*)d_in[7];
    const float* g4 = (const float*)d_in[8];
    const float* v5 = (const float*)d_in[9];
    const float* g5 = (const float*)d_in[10];
    float* out = (float*)d_out;

    const int M = 65536;
    char* ws = (char*)d_ws;
    u16* bufA = (u16*)(ws);                          // 128 MB
    u16* bufB = (u16*)(ws + 0x8000000ULL);           // 128 MB
    u16* w1T  = (u16*)(ws + 0x10000000ULL);
    u16* w2T  = w1T + 1024 * 512;
    u16* w3T  = w2T + 1024 * 1024;
    u16* w4T  = w3T + 1024 * 1024;
    u16* w5T  = w4T + 1024 * 1024;
    float* partial = (float*)(ws + 0x10800000ULL);
    float* scale   = partial + 8 * 1024;

    cvt_x_kernel<<<(M * 512) / (256 * 8), 256, 0, stream>>>((const float4*)x, bufB);

    auto prep = [&](const float* v, const float* g, u16* wT, int K, int N) {
        wn_partial<<<dim3(N / 64, 8), 256, 0, stream>>>(v, partial, K, N);
        wn_scale<<<(N + 255) / 256, 256, 0, stream>>>(partial, g, scale, N);
        wn_write<<<dim3(N / 64, 8), 256, 0, stream>>>(v, scale, wT, K, N);
    };
    prep(v1, g1, w1T, 512, 1024);
    prep(v2, g2, w2T, 1024, 1024);
    prep(v3, g3, w3T, 1024, 1024);
    prep(v4, g4, w4T, 1024, 1024);
    prep(v5, g5, w5T, 1024, 512);

    gemm_mlp<1024, 512,  true,  false><<<1024, 512, 0, stream>>>(bufB, w1T, bufA, nullptr);
    gemm_mlp<1024, 1024, true,  false><<<1024, 512, 0, stream>>>(bufA, w2T, bufB, nullptr);
    gemm_mlp<1024, 1024, true,  false><<<1024, 512, 0, stream>>>(bufB, w3T, bufA, nullptr);
    gemm_mlp<1024, 1024, true,  false><<<1024, 512, 0, stream>>>(bufA, w4T, bufB, nullptr);
    gemm_mlp<512,  1024, false, true ><<<512,  512, 0, stream>>>(bufB, w5T, nullptr, out);

    (void)in_sizes; (void)n_in; (void)out_size; (void)ws_size;
}